// Round 2
// baseline (349.307 us; speedup 1.0000x reference)
//
#include <hip/hip_runtime.h>
#include <hip/hip_bf16.h>

// Problem constants (from reference setup_inputs)
#define D     128
#define K0    50
#define NCOL  51      // output columns: 50 (centers0) + 1 (centers1)
#define NT    12      // 192 GEMM cols = 8 z_rot tiles + 4 cross tiles
#define TB    256     // batch rows per block (4 row-tiles per wave)

typedef __attribute__((ext_vector_type(4))) float  f32x4;
typedef __attribute__((ext_vector_type(8))) short  short8x;  // 8 bf16 in 4 VGPRs

__device__ inline short f2bf(float x) {
    __hip_bfloat16 h = __float2bfloat16(x);
    return __builtin_bit_cast(short, h);
}

// ---------------------------------------------------------------------------
// Setup: build G = [V | M0 | M1 | 0] (128 x 192) in bf16, stored in MFMA
// B-fragment order: Gws[blk=(ks*12+nt)][lane][j] = G[ks*32+(lane>>4)*8+j]
//                                                   [nt*16+(lane&15)]
//   cols 0..127   : V itself (z_rot = z @ V)        -> pure copy/convert
//   cols 128..177 : M0[:,k] = V (beta0 . c0[k])     -> 51 matvecs, LDS-transposed
//   col  178      : M1      = V (beta1 . c1[0])
// Block 48: cc[k] (beta-weighted center norms) + beta0 as float[128].
// ---------------------------------------------------------------------------
__global__ __launch_bounds__(128) void setup_kernel(
    const float* __restrict__ bw,   // [2][128]
    const float* __restrict__ V,    // [128][128]
    const float* __restrict__ c0,   // [50][128]
    const float* __restrict__ c1,   // [1][128]
    short* __restrict__ Gws,        // bf16 frag layout [48][64][8]
    float* __restrict__ ccws,       // [51]
    float* __restrict__ betaws)     // [128]
{
    const int blk = blockIdx.x;
    const int t   = threadIdx.x;
    __shared__ float beta0[D];
    __shared__ float Vt[D * 33];    // V[ks*32+d][e] transposed -> Vt[e*33+d]
    __shared__ float wct[D * 17];   // (beta.c)[k][e] transposed -> wct[e*17+k]

    if (t < D) {
        float b0 = bw[t], b1 = bw[D + t];
        beta0[t] = 1.0f / (1.0f + expf(b1 - b0));   // softmax over axis 0
    }
    __syncthreads();

    if (blk == 48) {                 // cc terms + beta float dump
        if (t < D) betaws[t] = beta0[t];
        if (t < NCOL) {
            const float* cr = (t < K0) ? (c0 + (size_t)t * D) : c1;
            float s = 0.f;
            for (int e = 0; e < D; ++e) {
                float b = (t == K0) ? (1.0f - beta0[e]) : beta0[e];
                float cv = cr[e];
                s += b * cv * cv;
            }
            ccws[t] = s;
        }
        return;
    }

    const int kstep = blk / NT;      // 0..3
    const int ntile = blk % NT;      // 0..11
    const int lane  = t >> 1;
    const int jbase = (t & 1) * 4;
    const int nl    = lane & 15;

    if (ntile < 8) {                 // G col = V col: copy/convert
        const int n = ntile * 16 + nl;
        short* dst = Gws + ((size_t)(blk * 64 + lane)) * 8 + jbase;
        for (int jj = 0; jj < 4; ++jj) {
            int d = kstep * 32 + (lane >> 4) * 8 + jbase + jj;
            dst[jj] = f2bf(V[(size_t)d * D + n]);
        }
        return;
    }

    // cross tiles: stage V rows (transposed) and beta-weighted centers
    for (int i = t; i < 32 * D; i += 128) {
        int d = i >> 7, e = i & 127;              // consecutive t -> consecutive e
        Vt[e * 33 + d] = V[(size_t)(kstep * 32 + d) * D + e];
    }
    for (int i = t; i < 16 * D; i += 128) {
        int kl = i >> 7, e = i & 127;
        int k = (ntile - 8) * 16 + kl;
        float w = 0.f;
        if (k < K0)       w = beta0[e] * c0[(size_t)k * D + e];
        else if (k == K0) w = (1.0f - beta0[e]) * c1[e];
        wct[e * 17 + kl] = w;
    }
    __syncthreads();

    short res[4];
    for (int jj = 0; jj < 4; ++jj) {
        int dl = (lane >> 4) * 8 + jbase + jj;    // 0..31
        float s = 0.f;
        #pragma unroll 8
        for (int e = 0; e < D; ++e)
            s += Vt[e * 33 + dl] * wct[e * 17 + nl];   // bank-conflict-free
        res[jj] = f2bf(s);
    }
    short* dst = Gws + ((size_t)(blk * 64 + lane)) * 8 + jbase;
    for (int jj = 0; jj < 4; ++jj) dst[jj] = res[jj];
}

// ---------------------------------------------------------------------------
// Main: per block, 256 rows (4 row-tiles of 16 per wave). Y = z @ G via
// mfma_f32_16x16x32_bf16. Tiles 0..7 of Y are z_rot; epilogue computes
// zz0 = sum beta0[n] z_rot[n]^2, nrm = sum z_rot[n]^2 from registers
// (V orthogonal => nrm = |z|^2), then out[b,k] = zz + cc[k] - 2*Y[:,128+k].
// No barriers inside the row-tile loop; no LDS traffic besides Gs reads.
// ---------------------------------------------------------------------------
__global__ __launch_bounds__(256, 3) void main_kernel(
    const float* __restrict__ z,      // [B][128]
    const short* __restrict__ Gws,    // bf16 frag layout [48][64][8]
    const float* __restrict__ ccws,   // [51]
    const float* __restrict__ betaws, // [128]
    float* __restrict__ out)          // [B][51]
{
    __shared__ __align__(16) short Gs[48 * 64 * 8];  // 49152 B -> 3 blocks/CU

    const int t    = threadIdx.x;
    const int wave = t >> 6;
    const int lane = t & 63;
    const int c    = lane & 15;     // MFMA m / n index within tile
    const int q    = lane >> 4;     // quad
    const size_t rowbase = (size_t)blockIdx.x * TB;

    // ---- stage G (48 KB, L2-resident source) ----
    for (int i = t; i < 48 * 64 * 8 / 8; i += 256)
        ((int4*)Gs)[i] = ((const int4*)Gws)[i];

    // ---- per-lane constants: beta at this lane's 8 z_rot cols, cc at its ks ----
    float breg[8];
    #pragma unroll
    for (int nt = 0; nt < 8; ++nt) breg[nt] = betaws[nt * 16 + c];
    float creg[4];
    #pragma unroll
    for (int j = 0; j < 4; ++j) {
        int kk = j * 16 + c;
        creg[j] = (kk <= K0) ? ccws[kk] : 0.f;
    }
    __syncthreads();

    for (int rt = 0; rt < 4; ++rt) {
        const int rowloc = (wave * 4 + rt) * 16;              // this tile's first row
        const float* zrow = z + (rowbase + rowloc + c) * D;

        // A fragments straight from global in fragment order
        short8x afrag[4];
        #pragma unroll
        for (int ks = 0; ks < 4; ++ks) {
            const float* p = zrow + ks * 32 + q * 8;
            f32x4 v0 = *(const f32x4*)p;
            f32x4 v1 = *(const f32x4*)(p + 4);
            short8x a;
            a[0] = f2bf(v0.x); a[1] = f2bf(v0.y); a[2] = f2bf(v0.z); a[3] = f2bf(v0.w);
            a[4] = f2bf(v1.x); a[5] = f2bf(v1.y); a[6] = f2bf(v1.z); a[7] = f2bf(v1.w);
            afrag[ks] = a;
        }

        f32x4 acc[NT];
        #pragma unroll
        for (int nt = 0; nt < NT; ++nt) acc[nt] = f32x4{0.f, 0.f, 0.f, 0.f};
        #pragma unroll
        for (int ks = 0; ks < 4; ++ks) {
            #pragma unroll
            for (int nt = 0; nt < NT; ++nt) {
                short8x bfrg = *(const short8x*)&Gs[((ks * NT + nt) * 64 + lane) * 8];
                acc[nt] = __builtin_amdgcn_mfma_f32_16x16x32_bf16(afrag[ks], bfrg, acc[nt], 0, 0, 0);
            }
        }

        // ---- epilogue from registers: C layout row=q*4+r, col=c ----
        float qp[4] = {0.f, 0.f, 0.f, 0.f};
        float np_[4] = {0.f, 0.f, 0.f, 0.f};
        #pragma unroll
        for (int nt = 0; nt < 8; ++nt) {
            #pragma unroll
            for (int r = 0; r < 4; ++r) {
                float y = acc[nt][r];
                float y2 = y * y;
                np_[r] += y2;
                qp[r] += breg[nt] * y2;
            }
        }
        #pragma unroll
        for (int s = 1; s < 16; s <<= 1) {
            #pragma unroll
            for (int r = 0; r < 4; ++r) {
                qp[r]  += __shfl_xor(qp[r], s, 64);
                np_[r] += __shfl_xor(np_[r], s, 64);
            }
        }

        const size_t rowg = rowbase + rowloc + q * 4;
        #pragma unroll
        for (int j = 0; j < 4; ++j) {
            int kk = j * 16 + c;
            if (kk <= K0) {
                #pragma unroll
                for (int r = 0; r < 4; ++r) {
                    float zz = (kk < K0) ? qp[r] : (np_[r] - qp[r]);
                    out[(rowg + r) * NCOL + kk] = zz + creg[j] - 2.0f * acc[8 + j][r];
                }
            }
        }
    }
}

extern "C" void kernel_launch(void* const* d_in, const int* in_sizes, int n_in,
                              void* d_out, int out_size, void* d_ws, size_t ws_size,
                              hipStream_t stream) {
    const float* z  = (const float*)d_in[0];
    const float* bw = (const float*)d_in[1];
    const float* V  = (const float*)d_in[2];
    const float* c0 = (const float*)d_in[3];
    const float* c1 = (const float*)d_in[4];
    float* out = (float*)d_out;

    short* Gws    = (short*)d_ws;                                  // 49152 B
    float* ccws   = (float*)((char*)d_ws + 48 * 64 * 8 * 2);       // 51 floats
    float* betaws = ccws + 64;                                     // 128 floats

    const int B = in_sizes[0] / D;   // 262144

    setup_kernel<<<49, 128, 0, stream>>>(bw, V, c0, c1, Gws, ccws, betaws);
    main_kernel<<<B / TB, 256, 0, stream>>>(z, Gws, ccws, betaws, out);
}

// Round 3
// 233.045 us; speedup vs baseline: 1.4989x; 1.4989x over previous
//
#include <hip/hip_runtime.h>
#include <hip/hip_bf16.h>

// Problem constants (from reference setup_inputs)
#define D     128
#define K0    50
#define NCOL  51      // output columns: 50 (centers0) + 1 (centers1)
#define NT    12      // 192 GEMM cols = 8 z_rot tiles + 4 cross tiles
#define TB    256     // batch rows per block (4 row-tiles per wave)

typedef __attribute__((ext_vector_type(4))) float  f32x4;
typedef __attribute__((ext_vector_type(8))) short  short8x;  // 8 bf16 in 4 VGPRs
// alignment-reduced vector types: out rows are 204 B, stores are only 4B-aligned
typedef f32x4 __attribute__((aligned(4))) f32x4u;
typedef __attribute__((ext_vector_type(2))) float f32x2;
typedef f32x2 __attribute__((aligned(4))) f32x2u;

__device__ inline short f2bf(float x) {
    __hip_bfloat16 h = __float2bfloat16(x);
    return __builtin_bit_cast(short, h);
}

// ---------------------------------------------------------------------------
// Setup: build G (128 x 192) in bf16 MFMA fragment order:
//   Gws[blk=(ks*12+nt)][lane][j] = G[ks*32+(lane>>4)*8+j][nt*16+(lane&15)]
//   tiles 0..7  : V itself (z_rot = z @ V), unscaled       (used as B operand)
//   tiles 8..11 : -2 * M, M[:,k] = V (beta . c_k)          (used as A operand:
//                 same storage reads as A[m=k][kdim=d] = -2*Mt[k][d])
// Block 48: cc[k] (beta-weighted center norms) + beta0 as float[128].
// ---------------------------------------------------------------------------
__global__ __launch_bounds__(128) void setup_kernel(
    const float* __restrict__ bw,   // [2][128]
    const float* __restrict__ V,    // [128][128]
    const float* __restrict__ c0,   // [50][128]
    const float* __restrict__ c1,   // [1][128]
    short* __restrict__ Gws,        // bf16 frag layout [48][64][8]
    float* __restrict__ ccws,       // [51]
    float* __restrict__ betaws)     // [128]
{
    const int blk = blockIdx.x;
    const int t   = threadIdx.x;
    __shared__ float beta0[D];
    __shared__ float Vt[D * 33];    // V[ks*32+d][e] transposed -> Vt[e*33+d]
    __shared__ float wct[D * 17];   // (beta.c)[k][e] transposed -> wct[e*17+k]

    if (t < D) {
        float b0 = bw[t], b1 = bw[D + t];
        beta0[t] = 1.0f / (1.0f + expf(b1 - b0));   // softmax over axis 0
    }
    __syncthreads();

    if (blk == 48) {                 // cc terms + beta float dump
        if (t < D) betaws[t] = beta0[t];
        if (t < NCOL) {
            const float* cr = (t < K0) ? (c0 + (size_t)t * D) : c1;
            float s = 0.f;
            for (int e = 0; e < D; ++e) {
                float b = (t == K0) ? (1.0f - beta0[e]) : beta0[e];
                float cv = cr[e];
                s += b * cv * cv;
            }
            ccws[t] = s;
        }
        return;
    }

    const int kstep = blk / NT;      // 0..3
    const int ntile = blk % NT;      // 0..11
    const int lane  = t >> 1;
    const int jbase = (t & 1) * 4;
    const int nl    = lane & 15;

    if (ntile < 8) {                 // G col = V col: copy/convert
        const int n = ntile * 16 + nl;
        short* dst = Gws + ((size_t)(blk * 64 + lane)) * 8 + jbase;
        for (int jj = 0; jj < 4; ++jj) {
            int d = kstep * 32 + (lane >> 4) * 8 + jbase + jj;
            dst[jj] = f2bf(V[(size_t)d * D + n]);
        }
        return;
    }

    // cross tiles: stage V rows (transposed) and beta-weighted centers
    for (int i = t; i < 32 * D; i += 128) {
        int d = i >> 7, e = i & 127;              // consecutive t -> consecutive e
        Vt[e * 33 + d] = V[(size_t)(kstep * 32 + d) * D + e];
    }
    for (int i = t; i < 16 * D; i += 128) {
        int kl = i >> 7, e = i & 127;
        int k = (ntile - 8) * 16 + kl;
        float w = 0.f;
        if (k < K0)       w = beta0[e] * c0[(size_t)k * D + e];
        else if (k == K0) w = (1.0f - beta0[e]) * c1[e];
        wct[e * 17 + kl] = w;
    }
    __syncthreads();

    short res[4];
    for (int jj = 0; jj < 4; ++jj) {
        int dl = (lane >> 4) * 8 + jbase + jj;    // 0..31
        float s = 0.f;
        #pragma unroll 8
        for (int e = 0; e < D; ++e)
            s += Vt[e * 33 + dl] * wct[e * 17 + nl];   // bank-conflict-free
        res[jj] = f2bf(-2.0f * s);                     // fold -2x into G
    }
    short* dst = Gws + ((size_t)(blk * 64 + lane)) * 8 + jbase;
    for (int jj = 0; jj < 4; ++jj) dst[jj] = res[jj];
}

// ---------------------------------------------------------------------------
// Main: per block, 256 rows (4 row-tiles of 16 per wave).
//   z_rot tiles:  accr[nt] = mfma(zfrag, Gfrag)   -> C[row=batch][col=feat]
//   cross tiles:  accc[j]  = mfma(Gfrag, zfrag)   -> C[row=k][col=batch]
// Cross result: lane(c,q) holds batch row c, k = j*16+4q..+3 contiguous in
// regs -> dwordx4 stores give full 64B sectors (kills R2's 3.2x write amp).
// zz0 = sum beta0*z_rot^2 (butterfly over c then redistribute); |z|^2 exact
// from the fp32 loads. out[b][k] = zz + cc[k] + accc (G already holds -2M).
// ---------------------------------------------------------------------------
__global__ __launch_bounds__(256, 3) void main_kernel(
    const float* __restrict__ z,      // [B][128]
    const short* __restrict__ Gws,    // bf16 frag layout [48][64][8]
    const float* __restrict__ ccws,   // [51]
    const float* __restrict__ betaws, // [128]
    float* __restrict__ out)          // [B][51]
{
    __shared__ __align__(16) short Gs[48 * 64 * 8];  // 49152 B -> 3 blocks/CU

    const int t    = threadIdx.x;
    const int wave = t >> 6;
    const int lane = t & 63;
    const int c    = lane & 15;
    const int q    = lane >> 4;
    const size_t rowbase = (size_t)blockIdx.x * TB;

    // ---- stage G (48 KB, L2-resident source) ----
    for (int i = t; i < 48 * 64 * 8 / 8; i += 256)
        ((int4*)Gs)[i] = ((const int4*)Gws)[i];

    // ---- per-lane constants ----
    float breg[8];
    #pragma unroll
    for (int nt = 0; nt < 8; ++nt) breg[nt] = betaws[nt * 16 + c];
    float ccreg[4][4];
    #pragma unroll
    for (int j = 0; j < 4; ++j)
        #pragma unroll
        for (int r = 0; r < 4; ++r) {
            int kk = j * 16 + q * 4 + r;
            ccreg[j][r] = (kk <= K0) ? ccws[kk] : 0.f;
        }
    __syncthreads();

    for (int rt = 0; rt < 4; ++rt) {
        const int rowloc = (wave * 4 + rt) * 16;
        const float* zrow = z + (rowbase + rowloc + c) * D;

        // z fragments (A and B views are the same layout); exact |z|^2 on the fly
        short8x zfrag[4];
        float nrm_p = 0.f;
        #pragma unroll
        for (int ks = 0; ks < 4; ++ks) {
            const float* p = zrow + ks * 32 + q * 8;
            f32x4 v0 = *(const f32x4*)p;
            f32x4 v1 = *(const f32x4*)(p + 4);
            nrm_p += v0.x*v0.x + v0.y*v0.y + v0.z*v0.z + v0.w*v0.w
                   + v1.x*v1.x + v1.y*v1.y + v1.z*v1.z + v1.w*v1.w;
            short8x a;
            a[0] = f2bf(v0.x); a[1] = f2bf(v0.y); a[2] = f2bf(v0.z); a[3] = f2bf(v0.w);
            a[4] = f2bf(v1.x); a[5] = f2bf(v1.y); a[6] = f2bf(v1.z); a[7] = f2bf(v1.w);
            zfrag[ks] = a;
        }

        f32x4 accr[8], accc[4];
        #pragma unroll
        for (int nt = 0; nt < 8; ++nt) accr[nt] = f32x4{0.f, 0.f, 0.f, 0.f};
        #pragma unroll
        for (int j = 0; j < 4; ++j)   accc[j]  = f32x4{0.f, 0.f, 0.f, 0.f};

        #pragma unroll
        for (int ks = 0; ks < 4; ++ks) {
            #pragma unroll
            for (int nt = 0; nt < 8; ++nt) {
                short8x bfrg = *(const short8x*)&Gs[((ks * NT + nt) * 64 + lane) * 8];
                accr[nt] = __builtin_amdgcn_mfma_f32_16x16x32_bf16(zfrag[ks], bfrg, accr[nt], 0, 0, 0);
            }
            #pragma unroll
            for (int j = 0; j < 4; ++j) {
                short8x afrg = *(const short8x*)&Gs[((ks * NT + 8 + j) * 64 + lane) * 8];
                accc[j] = __builtin_amdgcn_mfma_f32_16x16x32_bf16(afrg, zfrag[ks], accc[j], 0, 0, 0);
            }
        }

        // ---- zz0 = sum beta0 * z_rot^2 over features (C: row=q*4+r, col=c) ----
        float qp[4] = {0.f, 0.f, 0.f, 0.f};
        #pragma unroll
        for (int nt = 0; nt < 8; ++nt) {
            #pragma unroll
            for (int r = 0; r < 4; ++r) {
                float y = accr[nt][r];
                qp[r] += breg[nt] * y * y;
            }
        }
        #pragma unroll
        for (int s = 1; s < 16; s <<= 1) {
            #pragma unroll
            for (int r = 0; r < 4; ++r) qp[r] += __shfl_xor(qp[r], s, 64);
        }
        // exact |z|^2: reduce over the 4 lanes sharing this c (q varies)
        float nrm = nrm_p + __shfl_xor(nrm_p, 16, 64);
        nrm += __shfl_xor(nrm, 32, 64);

        // redistribute zz0 to batch-row-c indexing: row c -> quad c>>2, reg c&3
        float tq[4];
        const int srcl = (c >> 2) * 16;
        #pragma unroll
        for (int r = 0; r < 4; ++r) tq[r] = __shfl(qp[r], srcl, 64);
        float zz0 = (c & 2) ? ((c & 1) ? tq[3] : tq[2])
                            : ((c & 1) ? tq[1] : tq[0]);

        // ---- dense stores: lane(c,q) -> row c, k = j*16+4q..+3 ----
        float* orow = out + (rowbase + rowloc + c) * NCOL;
        #pragma unroll
        for (int j = 0; j < 3; ++j) {          // k = 0..47: all use zz0
            f32x4 v;
            #pragma unroll
            for (int r = 0; r < 4; ++r) v[r] = zz0 + ccreg[j][r] + accc[j][r];
            *(f32x4u*)(orow + j * 16 + q * 4) = v;
        }
        if (q == 0) {                          // k = 48,49 (zz0) and 50 (zz1)
            f32x2 v2;
            v2.x = zz0 + ccreg[3][0] + accc[3][0];
            v2.y = zz0 + ccreg[3][1] + accc[3][1];
            *(f32x2u*)(orow + 48) = v2;
            orow[50] = (nrm - zz0) + ccreg[3][2] + accc[3][2];
        }
    }
}

extern "C" void kernel_launch(void* const* d_in, const int* in_sizes, int n_in,
                              void* d_out, int out_size, void* d_ws, size_t ws_size,
                              hipStream_t stream) {
    const float* z  = (const float*)d_in[0];
    const float* bw = (const float*)d_in[1];
    const float* V  = (const float*)d_in[2];
    const float* c0 = (const float*)d_in[3];
    const float* c1 = (const float*)d_in[4];
    float* out = (float*)d_out;

    short* Gws    = (short*)d_ws;                                  // 49152 B
    float* ccws   = (float*)((char*)d_ws + 48 * 64 * 8 * 2);       // 51 floats
    float* betaws = ccws + 64;                                     // 128 floats

    const int B = in_sizes[0] / D;   // 262144

    setup_kernel<<<49, 128, 0, stream>>>(bw, V, c0, c1, Gws, ccws, betaws);
    main_kernel<<<B / TB, 256, 0, stream>>>(z, Gws, ccws, betaws, out);
}